// Round 1
// baseline (2644.700 us; speedup 1.0000x reference)
//
#include <hip/hip_runtime.h>
#include <hip/hip_bf16.h>
#include <math.h>

#define D_MODEL 1024
#define INTER   1024
#define NEXP    8
#define T_TOK   8192
#define BM      128
#define BN      128
#define BK      8
// worst-case padded routed rows: 2*T + 8*(BM-1) rounded up to BM
#define ROWCAP  17408

// ---------------- gate: logits -> softmax -> top2 -> counts ----------------
__global__ void k_gate(const float* __restrict__ X, const float* __restrict__ GW,
                       int* __restrict__ topk_idx, float* __restrict__ topk_w,
                       int* __restrict__ cnt)
{
    const int t = blockIdx.x;
    const int lane = threadIdx.x;
    const float* xr = X + (size_t)t * D_MODEL;
    float p[NEXP];
#pragma unroll
    for (int e = 0; e < NEXP; ++e) p[e] = 0.f;
    for (int i = lane; i < D_MODEL; i += 64) {
        float xv = xr[i];
#pragma unroll
        for (int e = 0; e < NEXP; ++e) p[e] += xv * GW[e * D_MODEL + i];
    }
#pragma unroll
    for (int e = 0; e < NEXP; ++e) {
#pragma unroll
        for (int off = 32; off > 0; off >>= 1)
            p[e] += __shfl_xor(p[e], off, 64);
    }
    if (lane == 0) {
        float m = p[0];
#pragma unroll
        for (int e = 1; e < NEXP; ++e) m = fmaxf(m, p[e]);
        float s = 0.f, sc[NEXP];
#pragma unroll
        for (int e = 0; e < NEXP; ++e) { sc[e] = __expf(p[e] - m); s += sc[e]; }
        float inv = 1.f / s;
#pragma unroll
        for (int e = 0; e < NEXP; ++e) sc[e] *= inv;
        // top-1 (ties -> lowest index, matches lax.top_k)
        int i0 = 0; float v0 = sc[0];
#pragma unroll
        for (int e = 1; e < NEXP; ++e) if (sc[e] > v0) { v0 = sc[e]; i0 = e; }
        // top-2
        int i1 = -1; float v1 = -1e30f;
#pragma unroll
        for (int e = 0; e < NEXP; ++e) if (e != i0 && sc[e] > v1) { v1 = sc[e]; i1 = e; }
        topk_idx[2 * t]     = i0;
        topk_idx[2 * t + 1] = i1;
        topk_w[2 * t]       = v0;   // ROUTE_SCALE == 1.0
        topk_w[2 * t + 1]   = v1;
        atomicAdd(&cnt[i0], 1);
        atomicAdd(&cnt[i1], 1);
    }
}

// ---------------- prefix: padded per-expert segment offsets ----------------
__global__ void k_prefix(const int* __restrict__ cnt, int* __restrict__ offs)
{
    if (threadIdx.x == 0 && blockIdx.x == 0) {
        int tot = 0;
        for (int e = 0; e < NEXP; ++e) {
            offs[e] = tot;
            tot += ((cnt[e] + BM - 1) / BM) * BM;
        }
        offs[NEXP] = tot;
    }
}

// ---------------- scatter tokens into per-expert lists ----------------
__global__ void k_scatter(const int* __restrict__ topk_idx, const float* __restrict__ topk_w,
                          const int* __restrict__ offs, int* __restrict__ cnt2,
                          int* __restrict__ rowid, float* __restrict__ rowwt)
{
    int t = blockIdx.x * blockDim.x + threadIdx.x;
    if (t >= T_TOK) return;
#pragma unroll
    for (int k = 0; k < 2; ++k) {
        int e = topk_idx[2 * t + k];
        int slot = atomicAdd(&cnt2[e], 1);
        int pos = offs[e] + slot;
        rowid[pos] = t;
        rowwt[pos] = topk_w[2 * t + k];
    }
}

// ---------------- H = silu(X@W1+b1) * (X@W3+b3), fp32 tiled ----------------
template <bool ROUTED>
__global__ __launch_bounds__(256, 2)
void k_h(const float* __restrict__ X,
         const float* __restrict__ W1, const float* __restrict__ B1,
         const float* __restrict__ W3, const float* __restrict__ B3,
         float* __restrict__ H,
         const int* __restrict__ rowid, const int* __restrict__ offs,
         const int* __restrict__ cnt)
{
    __shared__ __align__(16) float As [BK][BM + 4];
    __shared__ __align__(16) float B1s[BK][BN + 4];
    __shared__ __align__(16) float B3s[BK][BN + 4];

    const int nb   = blockIdx.x * BN;
    const int row0 = blockIdx.y * BM;

    int rstart = 0, rcount = T_TOK;
    if constexpr (ROUTED) {
        int total = offs[NEXP];
        if (row0 >= total) return;
        int e = 0;
        while (offs[e + 1] <= row0) ++e;
        rstart = offs[e];
        rcount = cnt[e];
        W1 += (size_t)e * D_MODEL * INTER;  B1 += e * INTER;
        W3 += (size_t)e * D_MODEL * INTER;  B3 += e * INTER;
    }

    const int t = threadIdx.x;
    // A staging: 128 rows x 8 k, one float4/thread
    const int am = t >> 1;
    const int ak = (t & 1) * 4;
    const int arow = row0 + am;
    bool avalid; int asrc;
    if constexpr (ROUTED) {
        avalid = (arow - rstart) < rcount;
        asrc = avalid ? rowid[arow] : 0;
    } else {
        avalid = true; asrc = arow;
    }
    const float* Aptr = X + (size_t)asrc * D_MODEL + ak;
    // B staging: 8 k x 128 n, one float4/thread per matrix
    const int bk = t >> 5;
    const int bn = (t & 31) * 4;
    const float* B1p = W1 + (size_t)bk * INTER + nb + bn;
    const float* B3p = W3 + (size_t)bk * INTER + nb + bn;
    // output mapping: 8x8 per thread
    const int tn = (t & 15) * 8;
    const int tm = (t >> 4) * 8;

    float acc1[8][8], acc3[8][8];
#pragma unroll
    for (int i = 0; i < 8; ++i)
#pragma unroll
        for (int j = 0; j < 8; ++j) { acc1[i][j] = 0.f; acc3[i][j] = 0.f; }

    for (int kt = 0; kt < D_MODEL; kt += BK) {
        float4 av  = avalid ? *(const float4*)(Aptr + kt) : make_float4(0.f, 0.f, 0.f, 0.f);
        float4 b1v = *(const float4*)(B1p + (size_t)kt * INTER);
        float4 b3v = *(const float4*)(B3p + (size_t)kt * INTER);
        __syncthreads();
        As[ak + 0][am] = av.x; As[ak + 1][am] = av.y;
        As[ak + 2][am] = av.z; As[ak + 3][am] = av.w;
        *(float4*)&B1s[bk][bn] = b1v;
        *(float4*)&B3s[bk][bn] = b3v;
        __syncthreads();
#pragma unroll
        for (int kk = 0; kk < BK; ++kk) {
            float a[8], bb1[8], bb3[8];
            *(float4*)&a[0]   = *(const float4*)&As [kk][tm];
            *(float4*)&a[4]   = *(const float4*)&As [kk][tm + 4];
            *(float4*)&bb1[0] = *(const float4*)&B1s[kk][tn];
            *(float4*)&bb1[4] = *(const float4*)&B1s[kk][tn + 4];
            *(float4*)&bb3[0] = *(const float4*)&B3s[kk][tn];
            *(float4*)&bb3[4] = *(const float4*)&B3s[kk][tn + 4];
#pragma unroll
            for (int i = 0; i < 8; ++i)
#pragma unroll
                for (int j = 0; j < 8; ++j) {
                    acc1[i][j] += a[i] * bb1[j];
                    acc3[i][j] += a[i] * bb3[j];
                }
        }
    }

    float bias1[8], bias3[8];
#pragma unroll
    for (int j = 0; j < 8; ++j) { bias1[j] = B1[nb + tn + j]; bias3[j] = B3[nb + tn + j]; }
#pragma unroll
    for (int i = 0; i < 8; ++i) {
        const int r = row0 + tm + i;
        float hv[8];
#pragma unroll
        for (int j = 0; j < 8; ++j) {
            float x1 = acc1[i][j] + bias1[j];
            float x3 = acc3[i][j] + bias3[j];
            hv[j] = x1 / (1.f + __expf(-x1)) * x3;   // silu(x1) * x3
        }
        float4* Hp = (float4*)(H + (size_t)r * INTER + nb + tn);
        Hp[0] = *(float4*)&hv[0];
        Hp[1] = *(float4*)&hv[4];
    }
}

// ---------------- out (+)= w * (H@W2 + b2), fp32 tiled ----------------
template <bool ROUTED>
__global__ __launch_bounds__(256, 2)
void k_out(const float* __restrict__ Hin,
           const float* __restrict__ W2, const float* __restrict__ B2,
           float* __restrict__ out,
           const int* __restrict__ rowid, const int* __restrict__ offs,
           const int* __restrict__ cnt, const float* __restrict__ rowwt)
{
    __shared__ __align__(16) float As[BK][BM + 4];
    __shared__ __align__(16) float Bs[BK][BN + 4];

    const int nb   = blockIdx.x * BN;
    const int row0 = blockIdx.y * BM;

    int rstart = 0, rcount = T_TOK;
    if constexpr (ROUTED) {
        int total = offs[NEXP];
        if (row0 >= total) return;
        int e = 0;
        while (offs[e + 1] <= row0) ++e;
        rstart = offs[e];
        rcount = cnt[e];
        W2 += (size_t)e * INTER * D_MODEL;  B2 += e * D_MODEL;
    }

    const int t = threadIdx.x;
    const int am = t >> 1;
    const int ak = (t & 1) * 4;
    const float* Aptr = Hin + (size_t)(row0 + am) * INTER + ak;  // H rows are slot-indexed
    const int bk = t >> 5;
    const int bn = (t & 31) * 4;
    const float* Bp = W2 + (size_t)bk * D_MODEL + nb + bn;
    const int tn = (t & 15) * 8;
    const int tm = (t >> 4) * 8;

    float acc[8][8];
#pragma unroll
    for (int i = 0; i < 8; ++i)
#pragma unroll
        for (int j = 0; j < 8; ++j) acc[i][j] = 0.f;

    for (int kt = 0; kt < INTER; kt += BK) {
        float4 av = *(const float4*)(Aptr + kt);
        float4 bv = *(const float4*)(Bp + (size_t)kt * D_MODEL);
        __syncthreads();
        As[ak + 0][am] = av.x; As[ak + 1][am] = av.y;
        As[ak + 2][am] = av.z; As[ak + 3][am] = av.w;
        *(float4*)&Bs[bk][bn] = bv;
        __syncthreads();
#pragma unroll
        for (int kk = 0; kk < BK; ++kk) {
            float a[8], bb[8];
            *(float4*)&a[0]  = *(const float4*)&As[kk][tm];
            *(float4*)&a[4]  = *(const float4*)&As[kk][tm + 4];
            *(float4*)&bb[0] = *(const float4*)&Bs[kk][tn];
            *(float4*)&bb[4] = *(const float4*)&Bs[kk][tn + 4];
#pragma unroll
            for (int i = 0; i < 8; ++i)
#pragma unroll
                for (int j = 0; j < 8; ++j)
                    acc[i][j] += a[i] * bb[j];
        }
    }

    float bias2[8];
#pragma unroll
    for (int j = 0; j < 8; ++j) bias2[j] = B2[nb + tn + j];

#pragma unroll
    for (int i = 0; i < 8; ++i) {
        const int r = row0 + tm + i;
        if constexpr (ROUTED) {
            const int slotl = r - rstart;
            if (slotl < rcount) {
                const int tok = rowid[r];
                const float w = rowwt[r];
                float* orow = out + (size_t)tok * D_MODEL + nb + tn;
#pragma unroll
                for (int j = 0; j < 8; ++j)
                    atomicAdd(&orow[j], w * (acc[i][j] + bias2[j]));
            }
        } else {
            float ov[8];
#pragma unroll
            for (int j = 0; j < 8; ++j) ov[j] = acc[i][j] + bias2[j];
            float4* op = (float4*)(out + (size_t)r * D_MODEL + nb + tn);
            op[0] = *(float4*)&ov[0];
            op[1] = *(float4*)&ov[4];
        }
    }
}

// ---------------- launcher ----------------
extern "C" void kernel_launch(void* const* d_in, const int* in_sizes, int n_in,
                              void* d_out, int out_size, void* d_ws, size_t ws_size,
                              hipStream_t stream)
{
    const float* x   = (const float*)d_in[0];
    const float* gw  = (const float*)d_in[1];
    const float* w1  = (const float*)d_in[2];
    const float* b1  = (const float*)d_in[3];
    const float* w2  = (const float*)d_in[4];
    const float* b2  = (const float*)d_in[5];
    const float* w3  = (const float*)d_in[6];
    const float* b3  = (const float*)d_in[7];
    const float* sw1 = (const float*)d_in[8];
    const float* sb1 = (const float*)d_in[9];
    const float* sw2 = (const float*)d_in[10];
    const float* sb2 = (const float*)d_in[11];
    const float* sw3 = (const float*)d_in[12];
    const float* sb3 = (const float*)d_in[13];
    float* out = (float*)d_out;

    char* ws = (char*)d_ws;
    int*   cnt      = (int*)(ws + 0);
    int*   cnt2     = (int*)(ws + 64);
    int*   offs     = (int*)(ws + 128);
    int*   topk_idx = (int*)(ws + 256);
    float* topk_w   = (float*)(ws + 256 + 2 * T_TOK * 4);
    int*   rowid    = (int*)(ws + 256 + 4 * T_TOK * 4);
    float* rowwt    = (float*)(ws + 256 + 4 * T_TOK * 4 + ROWCAP * 4);
    float* H        = (float*)(ws + (1 << 20));   // 71.3 MB at offset 1 MB

    hipMemsetAsync(ws, 0, 256, stream);  // zero cnt, cnt2

    k_gate<<<T_TOK, 64, 0, stream>>>(x, gw, topk_idx, topk_w, cnt);
    k_prefix<<<1, 64, 0, stream>>>(cnt, offs);
    k_scatter<<<T_TOK / 256, 256, 0, stream>>>(topk_idx, topk_w, offs, cnt2, rowid, rowwt);

    // shared expert first: plain stores initialize out (no memset of out needed)
    k_h<false><<<dim3(INTER / BN, T_TOK / BM), 256, 0, stream>>>(
        x, sw1, sb1, sw3, sb3, H, nullptr, nullptr, nullptr);
    k_out<false><<<dim3(D_MODEL / BN, T_TOK / BM), 256, 0, stream>>>(
        H, sw2, sb2, out, nullptr, nullptr, nullptr, nullptr);

    // routed experts: gathered rows, weighted atomic accumulate
    k_h<true><<<dim3(INTER / BN, ROWCAP / BM), 256, 0, stream>>>(
        x, w1, b1, w3, b3, H, rowid, offs, cnt);
    k_out<true><<<dim3(D_MODEL / BN, ROWCAP / BM), 256, 0, stream>>>(
        H, w2, b2, out, rowid, offs, cnt, rowwt);
}

// Round 2
// 798.389 us; speedup vs baseline: 3.3125x; 3.3125x over previous
//
#include <hip/hip_runtime.h>
#include <hip/hip_bf16.h>
#include <math.h>

#define D_MODEL 1024
#define INTER   1024
#define NEXP    8
#define T_TOK   8192
#define ROWCAP  17408   // 2*T + 8*127 padded up to 128

typedef short  short8 __attribute__((ext_vector_type(8)));
typedef float  f32x4  __attribute__((ext_vector_type(4)));

__device__ __forceinline__ ushort f2bf(float f) {
    uint u = __float_as_uint(f);
    u += 0x7fffu + ((u >> 16) & 1u);      // RNE (inputs finite)
    return (ushort)(u >> 16);
}
__device__ __forceinline__ uint pk2(float lo, float hi) {
    return (uint)f2bf(lo) | ((uint)f2bf(hi) << 16);
}

// ---------------- gate: logits -> softmax -> top2 -> counts (unchanged) ----
__global__ void k_gate(const float* __restrict__ X, const float* __restrict__ GW,
                       int* __restrict__ topk_idx, float* __restrict__ topk_w,
                       int* __restrict__ cnt)
{
    const int t = blockIdx.x;
    const int lane = threadIdx.x;
    const float* xr = X + (size_t)t * D_MODEL;
    float p[NEXP];
#pragma unroll
    for (int e = 0; e < NEXP; ++e) p[e] = 0.f;
    for (int i = lane; i < D_MODEL; i += 64) {
        float xv = xr[i];
#pragma unroll
        for (int e = 0; e < NEXP; ++e) p[e] += xv * GW[e * D_MODEL + i];
    }
#pragma unroll
    for (int e = 0; e < NEXP; ++e) {
#pragma unroll
        for (int off = 32; off > 0; off >>= 1)
            p[e] += __shfl_xor(p[e], off, 64);
    }
    if (lane == 0) {
        float m = p[0];
#pragma unroll
        for (int e = 1; e < NEXP; ++e) m = fmaxf(m, p[e]);
        float s = 0.f, sc[NEXP];
#pragma unroll
        for (int e = 0; e < NEXP; ++e) { sc[e] = __expf(p[e] - m); s += sc[e]; }
        float inv = 1.f / s;
#pragma unroll
        for (int e = 0; e < NEXP; ++e) sc[e] *= inv;
        int i0 = 0; float v0 = sc[0];
#pragma unroll
        for (int e = 1; e < NEXP; ++e) if (sc[e] > v0) { v0 = sc[e]; i0 = e; }
        int i1 = -1; float v1 = -1e30f;
#pragma unroll
        for (int e = 0; e < NEXP; ++e) if (e != i0 && sc[e] > v1) { v1 = sc[e]; i1 = e; }
        topk_idx[2 * t]     = i0;
        topk_idx[2 * t + 1] = i1;
        topk_w[2 * t]       = v0;
        topk_w[2 * t + 1]   = v1;
        atomicAdd(&cnt[i0], 1);
        atomicAdd(&cnt[i1], 1);
    }
}

__global__ void k_prefix(const int* __restrict__ cnt, int* __restrict__ offs)
{
    if (threadIdx.x == 0 && blockIdx.x == 0) {
        int tot = 0;
        for (int e = 0; e < NEXP; ++e) {
            offs[e] = tot;
            tot += ((cnt[e] + 127) / 128) * 128;
        }
        offs[NEXP] = tot;
    }
}

__global__ void k_scatter(const int* __restrict__ topk_idx, const float* __restrict__ topk_w,
                          const int* __restrict__ offs, int* __restrict__ cnt2,
                          int* __restrict__ rowid, float* __restrict__ rowwt)
{
    int t = blockIdx.x * blockDim.x + threadIdx.x;
    if (t >= T_TOK) return;
#pragma unroll
    for (int k = 0; k < 2; ++k) {
        int e = topk_idx[2 * t + k];
        int slot = atomicAdd(&cnt2[e], 1);
        int pos = offs[e] + slot;
        rowid[pos] = t;
        rowwt[pos] = topk_w[2 * t + k];
    }
}

// ------------- transpose + fp32->bf16 weight conversion: dst[n][k]=src[k][n]
__global__ void k_tw(const float* __restrict__ src, ushort* __restrict__ dst)
{
    __shared__ float tl[64][65];
    const int e = blockIdx.z;
    src += (size_t)e << 20;
    dst += (size_t)e << 20;
    const int kb = blockIdx.y * 64, nbb = blockIdx.x * 64;
    const int t = threadIdx.x;
    const int r = t >> 4, c4 = (t & 15) * 4;
#pragma unroll
    for (int i = 0; i < 4; ++i) {
        float4 v = *(const float4*)(src + (size_t)(kb + r + 16 * i) * 1024 + nbb + c4);
        tl[r + 16 * i][c4 + 0] = v.x; tl[r + 16 * i][c4 + 1] = v.y;
        tl[r + 16 * i][c4 + 2] = v.z; tl[r + 16 * i][c4 + 3] = v.w;
    }
    __syncthreads();
#pragma unroll
    for (int i = 0; i < 4; ++i) {
        ushort4 o;
        o.x = f2bf(tl[c4 + 0][r + 16 * i]);
        o.y = f2bf(tl[c4 + 1][r + 16 * i]);
        o.z = f2bf(tl[c4 + 2][r + 16 * i]);
        o.w = f2bf(tl[c4 + 3][r + 16 * i]);
        *(ushort4*)(dst + (size_t)(nbb + r + 16 * i) * 1024 + kb + c4) = o;
    }
}

// LDS chunk-swizzle: row stride 32 ushort (64B), 16B chunk at pos = c ^ ((row>>1)&3)
#define LDSIDX(row, chunk) ((row) * 32 + (((chunk) ^ (((row) >> 1) & 3)) * 8))

// ---------------- H = silu(X@W1+b1) * (X@W3+b3), bf16 MFMA ----------------
template <bool ROUTED>
__global__ __launch_bounds__(256, 2)
void k_h(const float* __restrict__ X,
         const ushort* __restrict__ W1t, const float* __restrict__ B1,
         const ushort* __restrict__ W3t, const float* __restrict__ B3,
         ushort* __restrict__ Hb,
         const int* __restrict__ rowid, const int* __restrict__ offs,
         const int* __restrict__ cnt)
{
    __shared__ __align__(16) ushort As [128 * 32];
    __shared__ __align__(16) ushort B1s[128 * 32];
    __shared__ __align__(16) ushort B3s[128 * 32];

    const int nb   = blockIdx.x * 128;
    const int row0 = blockIdx.y * 128;

    int rstart = 0, rcount = T_TOK;
    if constexpr (ROUTED) {
        const int total = offs[NEXP];
        if (row0 >= total) return;
        int e = 0;
        while (offs[e + 1] <= row0) ++e;
        rstart = offs[e]; rcount = cnt[e];
        W1t += (size_t)e << 20; B1 += e * INTER;
        W3t += (size_t)e << 20; B3 += e * INTER;
    }

    const int t = threadIdx.x;
    // A staging: 2 threads/row, 16 floats each -> 2 swizzled 16B chunks
    const int srow  = t >> 1;
    const int shalf = t & 1;
    const int adst0 = LDSIDX(srow, 2 * shalf);
    const int adst1 = LDSIDX(srow, 2 * shalf + 1);
    int atok;
    if constexpr (ROUTED) {
        bool valid = (row0 + srow - rstart) < rcount;
        atok = valid ? rowid[row0 + srow] : 0;
    } else {
        atok = row0 + srow;
    }
    const float* Ap = X + (size_t)atok * D_MODEL + shalf * 16;

    // B staging: 4 threads/row (1 chunk each), rows brow and brow+64
    const int brow = t >> 2;
    const int bchk = t & 3;
    const ushort* B1p0 = W1t + (size_t)(nb + brow)      * 1024 + bchk * 8;
    const ushort* B1p1 = W1t + (size_t)(nb + brow + 64) * 1024 + bchk * 8;
    const ushort* B3p0 = W3t + (size_t)(nb + brow)      * 1024 + bchk * 8;
    const ushort* B3p1 = W3t + (size_t)(nb + brow + 64) * 1024 + bchk * 8;
    const int bdst0 = LDSIDX(brow, bchk);
    const int bdst1 = LDSIDX(brow + 64, bchk);

    // fragment addresses (loop-invariant)
    const int lane = t & 63, wid = t >> 6;
    const int wm = wid & 1, wn = wid >> 1;
    const int m16 = lane & 15, g = lane >> 4;
    int offA[4], offB[4];
#pragma unroll
    for (int i = 0; i < 4; ++i) {
        int r = wm * 64 + i * 16 + m16;
        offA[i] = LDSIDX(r, g);
        int n = wn * 64 + i * 16 + m16;
        offB[i] = LDSIDX(n, g);
    }

    const f32x4 zf = {0.f, 0.f, 0.f, 0.f};
    f32x4 acc1[4][4], acc3[4][4];
#pragma unroll
    for (int i = 0; i < 4; ++i)
#pragma unroll
        for (int j = 0; j < 4; ++j) { acc1[i][j] = zf; acc3[i][j] = zf; }

    for (int kt = 0; kt < D_MODEL; kt += 32) {
        float4 a0 = *(const float4*)(Ap + kt);
        float4 a1 = *(const float4*)(Ap + kt + 4);
        float4 a2 = *(const float4*)(Ap + kt + 8);
        float4 a3 = *(const float4*)(Ap + kt + 12);
        uint4 w1a = *(const uint4*)(B1p0 + kt);
        uint4 w1b = *(const uint4*)(B1p1 + kt);
        uint4 w3a = *(const uint4*)(B3p0 + kt);
        uint4 w3b = *(const uint4*)(B3p1 + kt);
        __syncthreads();
        uint4 t0 = { pk2(a0.x, a0.y), pk2(a0.z, a0.w), pk2(a1.x, a1.y), pk2(a1.z, a1.w) };
        uint4 t1 = { pk2(a2.x, a2.y), pk2(a2.z, a2.w), pk2(a3.x, a3.y), pk2(a3.z, a3.w) };
        *(uint4*)&As[adst0]  = t0;
        *(uint4*)&As[adst1]  = t1;
        *(uint4*)&B1s[bdst0] = w1a;
        *(uint4*)&B1s[bdst1] = w1b;
        *(uint4*)&B3s[bdst0] = w3a;
        *(uint4*)&B3s[bdst1] = w3b;
        __syncthreads();
        short8 af[4], b1f[4], b3f[4];
#pragma unroll
        for (int i = 0; i < 4; ++i) {
            af[i]  = *(const short8*)&As [offA[i]];
            b1f[i] = *(const short8*)&B1s[offB[i]];
            b3f[i] = *(const short8*)&B3s[offB[i]];
        }
#pragma unroll
        for (int i = 0; i < 4; ++i)
#pragma unroll
            for (int j = 0; j < 4; ++j) {
                acc1[i][j] = __builtin_amdgcn_mfma_f32_16x16x32_bf16(af[i], b1f[j], acc1[i][j], 0, 0, 0);
                acc3[i][j] = __builtin_amdgcn_mfma_f32_16x16x32_bf16(af[i], b3f[j], acc3[i][j], 0, 0, 0);
            }
    }

    // epilogue: bias + silu*mul, write bf16 H
#pragma unroll
    for (int j = 0; j < 4; ++j) {
        const int gcol = nb + wn * 64 + j * 16 + m16;
        const float bb1 = B1[gcol], bb3 = B3[gcol];
#pragma unroll
        for (int i = 0; i < 4; ++i) {
            const int growb = row0 + wm * 64 + i * 16 + g * 4;
#pragma unroll
            for (int r = 0; r < 4; ++r) {
                float x1 = acc1[i][j][r] + bb1;
                float x3 = acc3[i][j][r] + bb3;
                float h = x1 / (1.f + __expf(-x1)) * x3;
                Hb[(size_t)(growb + r) * INTER + gcol] = f2bf(h);
            }
        }
    }
}

// ---------------- out (+)= w * (H@W2 + b2), bf16 MFMA ----------------
template <bool ROUTED>
__global__ __launch_bounds__(256, 2)
void k_out(const ushort* __restrict__ Hin,
           const ushort* __restrict__ W2t, const float* __restrict__ B2,
           float* __restrict__ out,
           const int* __restrict__ rowid, const int* __restrict__ offs,
           const int* __restrict__ cnt, const float* __restrict__ rowwt)
{
    __shared__ __align__(16) ushort As[128 * 32];
    __shared__ __align__(16) ushort Bs[128 * 32];

    const int nb   = blockIdx.x * 128;
    const int row0 = blockIdx.y * 128;

    int rstart = 0, rcount = T_TOK;
    if constexpr (ROUTED) {
        const int total = offs[NEXP];
        if (row0 >= total) return;
        int e = 0;
        while (offs[e + 1] <= row0) ++e;
        rstart = offs[e]; rcount = cnt[e];
        W2t += (size_t)e << 20; B2 += e * D_MODEL;
    }

    const int t = threadIdx.x;
    // A staging from bf16 H: 4 threads/row, rows arow and arow+64
    const int arow = t >> 2;
    const int achk = t & 3;
    const ushort* Ap0 = Hin + (size_t)(row0 + arow)      * INTER + achk * 8;
    const ushort* Ap1 = Hin + (size_t)(row0 + arow + 64) * INTER + achk * 8;
    const int adst0 = LDSIDX(arow, achk);
    const int adst1 = LDSIDX(arow + 64, achk);
    // B staging
    const ushort* Bp0 = W2t + (size_t)(nb + arow)      * 1024 + achk * 8;
    const ushort* Bp1 = W2t + (size_t)(nb + arow + 64) * 1024 + achk * 8;

    const int lane = t & 63, wid = t >> 6;
    const int wm = wid & 1, wn = wid >> 1;
    const int m16 = lane & 15, g = lane >> 4;
    int offA[4], offB[4];
#pragma unroll
    for (int i = 0; i < 4; ++i) {
        int r = wm * 64 + i * 16 + m16;
        offA[i] = LDSIDX(r, g);
        int n = wn * 64 + i * 16 + m16;
        offB[i] = LDSIDX(n, g);
    }

    const f32x4 zf = {0.f, 0.f, 0.f, 0.f};
    f32x4 acc[4][4];
#pragma unroll
    for (int i = 0; i < 4; ++i)
#pragma unroll
        for (int j = 0; j < 4; ++j) acc[i][j] = zf;

    for (int kt = 0; kt < INTER; kt += 32) {
        uint4 av0 = *(const uint4*)(Ap0 + kt);
        uint4 av1 = *(const uint4*)(Ap1 + kt);
        uint4 bv0 = *(const uint4*)(Bp0 + kt);
        uint4 bv1 = *(const uint4*)(Bp1 + kt);
        __syncthreads();
        *(uint4*)&As[adst0] = av0;
        *(uint4*)&As[adst1] = av1;
        *(uint4*)&Bs[adst0] = bv0;
        *(uint4*)&Bs[adst1] = bv1;
        __syncthreads();
        short8 af[4], bf[4];
#pragma unroll
        for (int i = 0; i < 4; ++i) {
            af[i] = *(const short8*)&As[offA[i]];
            bf[i] = *(const short8*)&Bs[offB[i]];
        }
#pragma unroll
        for (int i = 0; i < 4; ++i)
#pragma unroll
            for (int j = 0; j < 4; ++j)
                acc[i][j] = __builtin_amdgcn_mfma_f32_16x16x32_bf16(af[i], bf[j], acc[i][j], 0, 0, 0);
    }

#pragma unroll
    for (int i = 0; i < 4; ++i) {
#pragma unroll
        for (int r = 0; r < 4; ++r) {
            const int grow = row0 + wm * 64 + i * 16 + g * 4 + r;
            int tok = grow; float wt = 1.f; bool valid = true;
            if constexpr (ROUTED) {
                valid = (grow - rstart) < rcount;
                if (valid) { tok = rowid[grow]; wt = rowwt[grow]; }
            }
            if (!valid) continue;
#pragma unroll
            for (int j = 0; j < 4; ++j) {
                const int gcol = nb + wn * 64 + j * 16 + m16;
                float v = acc[i][j][r] + B2[gcol];
                if constexpr (ROUTED) {
                    atomicAdd(out + (size_t)tok * D_MODEL + gcol, wt * v);
                } else {
                    out[(size_t)grow * D_MODEL + gcol] = v;
                }
            }
        }
    }
}

// ---------------- launcher ----------------
extern "C" void kernel_launch(void* const* d_in, const int* in_sizes, int n_in,
                              void* d_out, int out_size, void* d_ws, size_t ws_size,
                              hipStream_t stream)
{
    const float* x   = (const float*)d_in[0];
    const float* gw  = (const float*)d_in[1];
    const float* w1  = (const float*)d_in[2];
    const float* b1  = (const float*)d_in[3];
    const float* w2  = (const float*)d_in[4];
    const float* b2  = (const float*)d_in[5];
    const float* w3  = (const float*)d_in[6];
    const float* b3  = (const float*)d_in[7];
    const float* sw1 = (const float*)d_in[8];
    const float* sb1 = (const float*)d_in[9];
    const float* sw2 = (const float*)d_in[10];
    const float* sb2 = (const float*)d_in[11];
    const float* sw3 = (const float*)d_in[12];
    const float* sb3 = (const float*)d_in[13];
    float* out = (float*)d_out;

    char* ws = (char*)d_ws;
    int*   cnt      = (int*)(ws);
    int*   cnt2     = (int*)(ws + 64);
    int*   offs     = (int*)(ws + 128);
    int*   topk_idx = (int*)(ws + 256);
    float* topk_w   = (float*)(ws + 256 + 65536);
    int*   rowid    = (int*)(ws + 256 + 131072);
    float* rowwt    = (float*)(ws + 256 + 131072 + ROWCAP * 4);
    ushort* Hb   = (ushort*)(ws + (512 << 10));                 // 35.65 MB
    ushort* WREG = (ushort*)(ws + (size_t)36 * (1 << 20));      // 32 MB region, phase-reused
    ushort* sw1t = WREG;                    // shared phase
    ushort* sw3t = WREG + (1 << 20);
    ushort* sw2t = WREG + (2 << 20);
    ushort* w1t  = WREG;                    // routed phase (after shared done)
    ushort* w3t  = WREG + (8 << 20);
    ushort* w2t  = WREG;                    // after k_h<true> done

    hipMemsetAsync(ws, 0, 256, stream);     // cnt, cnt2

    // shared expert (initializes out with plain stores)
    k_tw<<<dim3(16, 16, 1), 256, 0, stream>>>(sw1, sw1t);
    k_tw<<<dim3(16, 16, 1), 256, 0, stream>>>(sw3, sw3t);
    k_h<false><<<dim3(8, 64), 256, 0, stream>>>(x, sw1t, sb1, sw3t, sb3, Hb,
                                                nullptr, nullptr, nullptr);
    k_tw<<<dim3(16, 16, 1), 256, 0, stream>>>(sw2, sw2t);
    k_out<false><<<dim3(8, 64), 256, 0, stream>>>(Hb, sw2t, sb2, out,
                                                  nullptr, nullptr, nullptr, nullptr);

    // routing
    k_gate<<<T_TOK, 64, 0, stream>>>(x, gw, topk_idx, topk_w, cnt);
    k_prefix<<<1, 64, 0, stream>>>(cnt, offs);
    k_scatter<<<T_TOK / 256, 256, 0, stream>>>(topk_idx, topk_w, offs, cnt2, rowid, rowwt);

    // routed experts (atomic accumulate into out)
    k_tw<<<dim3(16, 16, 8), 256, 0, stream>>>(w1, w1t);
    k_tw<<<dim3(16, 16, 8), 256, 0, stream>>>(w3, w3t);
    k_h<true><<<dim3(8, ROWCAP / 128), 256, 0, stream>>>(x, w1t, b1, w3t, b3, Hb,
                                                         rowid, offs, cnt);
    k_tw<<<dim3(16, 16, 8), 256, 0, stream>>>(w2, w2t);
    k_out<true><<<dim3(8, ROWCAP / 128), 256, 0, stream>>>(Hb, w2t, b2, out,
                                                           rowid, offs, cnt, rowwt);
}

// Round 5
// 615.471 us; speedup vs baseline: 4.2970x; 1.2972x over previous
//
#include <hip/hip_runtime.h>
#include <hip/hip_bf16.h>
#include <math.h>

#define D_MODEL 1024
#define INTER   1024
#define NEXP    8
#define T_TOK   8192
#define ROWCAP  17408   // 2*T + 8*127 padded up to 128

typedef short  short8 __attribute__((ext_vector_type(8)));
typedef float  f32x4  __attribute__((ext_vector_type(4)));

__device__ __forceinline__ ushort f2bf(float f) {
    uint u = __float_as_uint(f);
    u += 0x7fffu + ((u >> 16) & 1u);      // RNE (inputs finite)
    return (ushort)(u >> 16);
}
__device__ __forceinline__ uint pk2(float lo, float hi) {
    return (uint)f2bf(lo) | ((uint)f2bf(hi) << 16);
}
__device__ __forceinline__ void gll16(const ushort* g, ushort* l) {
    __builtin_amdgcn_global_load_lds(
        (const __attribute__((address_space(1))) unsigned int*)(g),
        (__attribute__((address_space(3))) unsigned int*)(l), 16, 0, 0);
}

// tiled-swizzled LDS/weight image: 128 rows x 64 k bf16; row stride 64 ushort;
// logical 16B chunk c (0..7) of row r sits at image chunk c ^ (r & 7).
#define IDX64(r, c) ((r) * 64 + (((c) ^ ((r) & 7)) * 8))

// ---------------- gate: GW in regs, 8 tokens/wave, butterfly reduce --------
__global__ __launch_bounds__(256)
void k_gate(const float* __restrict__ X, const float* __restrict__ GW,
            int* __restrict__ topk_idx, float* __restrict__ topk_w,
            int* __restrict__ cnt)
{
    __shared__ int lcnt[NEXP];
    const int t = threadIdx.x;
    if (t < NEXP) lcnt[t] = 0;
    const int lane = t & 63, wv = t >> 6;
    float4 gwr[NEXP][4];
#pragma unroll
    for (int e = 0; e < NEXP; ++e)
#pragma unroll
        for (int i = 0; i < 4; ++i)
            gwr[e][i] = *(const float4*)(GW + e * 1024 + i * 256 + lane * 4);
    __syncthreads();
    const int tok0 = blockIdx.x * 32 + wv * 8;
    const bool b0 = lane & 1, b1 = lane & 2, b2 = lane & 4;
    for (int tt = 0; tt < 8; ++tt) {
        const int tok = tok0 + tt;
        const float* xr = X + (size_t)tok * 1024;
        float4 xv[4];
#pragma unroll
        for (int i = 0; i < 4; ++i) xv[i] = *(const float4*)(xr + i * 256 + lane * 4);
        float p[NEXP];
#pragma unroll
        for (int e = 0; e < NEXP; ++e) {
            float s = 0.f;
#pragma unroll
            for (int i = 0; i < 4; ++i)
                s += xv[i].x * gwr[e][i].x + xv[i].y * gwr[e][i].y
                   + xv[i].z * gwr[e][i].z + xv[i].w * gwr[e][i].w;
            p[e] = s;
        }
        float q[4];
#pragma unroll
        for (int j = 0; j < 4; ++j) {
            float send = b0 ? p[j] : p[j + 4];
            float recv = __shfl_xor(send, 1, 64);
            q[j] = (b0 ? p[j + 4] : p[j]) + recv;
        }
        float u2[2];
#pragma unroll
        for (int j = 0; j < 2; ++j) {
            float send = b1 ? q[j] : q[j + 2];
            float recv = __shfl_xor(send, 2, 64);
            u2[j] = (b1 ? q[j + 2] : q[j]) + recv;
        }
        float send = b2 ? u2[0] : u2[1];
        float r = (b2 ? u2[1] : u2[0]) + __shfl_xor(send, 4, 64);
        r += __shfl_xor(r, 8, 64);
        r += __shfl_xor(r, 16, 64);
        r += __shfl_xor(r, 32, 64);
        float sc[NEXP];
#pragma unroll
        for (int e = 0; e < NEXP; ++e)
            sc[e] = __shfl(r, ((e & 1) << 2) | (e & 2) | ((e >> 2) & 1), 64);
        float m = sc[0];
#pragma unroll
        for (int e = 1; e < NEXP; ++e) m = fmaxf(m, sc[e]);
        float ssum = 0.f;
#pragma unroll
        for (int e = 0; e < NEXP; ++e) { sc[e] = __expf(sc[e] - m); ssum += sc[e]; }
        float inv = 1.f / ssum;
#pragma unroll
        for (int e = 0; e < NEXP; ++e) sc[e] *= inv;
        int i0 = 0; float v0 = sc[0];
#pragma unroll
        for (int e = 1; e < NEXP; ++e) if (sc[e] > v0) { v0 = sc[e]; i0 = e; }
        int i1 = -1; float v1 = -1e30f;
#pragma unroll
        for (int e = 0; e < NEXP; ++e) if (e != i0 && sc[e] > v1) { v1 = sc[e]; i1 = e; }
        if (lane == 0) {
            topk_idx[2 * tok]     = i0;
            topk_idx[2 * tok + 1] = i1;
            topk_w[2 * tok]       = v0;
            topk_w[2 * tok + 1]   = v1;
            atomicAdd(&lcnt[i0], 1);
            atomicAdd(&lcnt[i1], 1);
        }
    }
    __syncthreads();
    if (t < NEXP) atomicAdd(&cnt[t], lcnt[t]);
}

__global__ void k_prefix(const int* __restrict__ cnt, int* __restrict__ offs)
{
    if (threadIdx.x == 0 && blockIdx.x == 0) {
        int tot = 0;
        for (int e = 0; e < NEXP; ++e) {
            offs[e] = tot;
            tot += ((cnt[e] + 127) / 128) * 128;
        }
        offs[NEXP] = tot;
    }
}

// scatter with block-aggregated atomics
__global__ void k_scatter(const int* __restrict__ topk_idx, const float* __restrict__ topk_w,
                          const int* __restrict__ offs, int* __restrict__ cnt2,
                          int* __restrict__ rowid, float* __restrict__ rowwt)
{
    __shared__ int loc[NEXP];
    __shared__ int base[NEXP];
    const int t = threadIdx.x;
    if (t < NEXP) loc[t] = 0;
    __syncthreads();
    const int tok = blockIdx.x * 256 + t;
    const int e0 = topk_idx[2 * tok], e1 = topk_idx[2 * tok + 1];
    const int s0 = atomicAdd(&loc[e0], 1);
    const int s1 = atomicAdd(&loc[e1], 1);
    __syncthreads();
    if (t < NEXP) base[t] = atomicAdd(&cnt2[t], loc[t]);
    __syncthreads();
    int p0 = offs[e0] + base[e0] + s0;
    rowid[p0] = tok; rowwt[p0] = topk_w[2 * tok];
    int p1 = offs[e1] + base[e1] + s1;
    rowid[p1] = tok; rowwt[p1] = topk_w[2 * tok + 1];
}

// ------- transpose fp32 [K][N] -> tiled swizzled bf16 (128n x 64k tiles) ----
__global__ __launch_bounds__(256)
void k_tw(const float* __restrict__ srcA, ushort* __restrict__ dstA,
          const float* __restrict__ srcB, ushort* __restrict__ dstB, int nA)
{
    __shared__ float tl[64][132];
    int m = blockIdx.y;
    const float* src; ushort* dst;
    if (m < nA) { src = srcA + ((size_t)m << 20); dst = dstA + ((size_t)m << 20); }
    else { m -= nA;  src = srcB + ((size_t)m << 20); dst = dstB + ((size_t)m << 20); }
    const int tile = blockIdx.x;            // nb*16 + kt
    const int nb = tile >> 4, kt = tile & 15;
    const int t = threadIdx.x;
    const int c4 = (t & 31) * 4, kr = t >> 5;
#pragma unroll
    for (int i = 0; i < 8; ++i) {
        const int kl = kr + 8 * i;
        float4 v = *(const float4*)(src + (size_t)(kt * 64 + kl) * 1024 + nb * 128 + c4);
        tl[kl][c4 + 0] = v.x; tl[kl][c4 + 1] = v.y;
        tl[kl][c4 + 2] = v.z; tl[kl][c4 + 3] = v.w;
    }
    __syncthreads();
    const int nl = t >> 1, h = t & 1;
    ushort* drow = dst + (size_t)tile * 8192 + nl * 64;
#pragma unroll
    for (int w = 0; w < 4; ++w) {
        const int cimg = h * 4 + w;
        const int cl = cimg ^ (nl & 7);
        float f[8];
#pragma unroll
        for (int j = 0; j < 8; ++j) f[j] = tl[cl * 8 + j][nl];
        uint4 o = { pk2(f[0], f[1]), pk2(f[2], f[3]), pk2(f[4], f[5]), pk2(f[6], f[7]) };
        *(uint4*)(drow + cimg * 8) = o;
    }
}

// ---------------- H = silu(X@W1+b1) * (X@W3+b3), BK=64, gll B-staging ------
template <bool ROUTED>
__global__ __launch_bounds__(256, 2)
void k_h(const float* __restrict__ X,
         const ushort* __restrict__ W1t, const float* __restrict__ B1,
         const ushort* __restrict__ W3t, const float* __restrict__ B3,
         ushort* __restrict__ Hb,
         const int* __restrict__ rowid, const int* __restrict__ offs,
         const int* __restrict__ cnt)
{
    __shared__ __align__(16) ushort As [128 * 64];
    __shared__ __align__(16) ushort B1s[128 * 64];
    __shared__ __align__(16) ushort B3s[128 * 64];

    const int nbx  = blockIdx.x;            // 0..7
    const int nb   = nbx * 128;
    const int row0 = blockIdx.y * 128;

    int rstart = 0, rcount = T_TOK;
    const ushort* w1 = W1t; const ushort* w3 = W3t;
    if constexpr (ROUTED) {
        const int total = offs[NEXP];
        if (row0 >= total) return;
        int e = 0;
        while (offs[e + 1] <= row0) ++e;
        rstart = offs[e]; rcount = cnt[e];
        w1 += (size_t)e << 20; B1 += e * INTER;
        w3 += (size_t)e << 20; B3 += e * INTER;
    }
    const int t = threadIdx.x;
    const ushort* g1 = w1 + (size_t)(nbx * 16) * 8192 + t * 8;
    const ushort* g3 = w3 + (size_t)(nbx * 16) * 8192 + t * 8;

    // A staging: row = t>>1, half = t&1 -> 32 fp32 -> 4 swizzled uint4
    const int arow = t >> 1, ah = t & 1;
    int atok;
    if constexpr (ROUTED) {
        bool valid = (row0 + arow - rstart) < rcount;
        atok = valid ? rowid[row0 + arow] : 0;
    } else {
        atok = row0 + arow;
    }
    const float* Ap = X + (size_t)atok * D_MODEL + ah * 32;
    int aoff[4];
#pragma unroll
    for (int w = 0; w < 4; ++w) aoff[w] = IDX64(arow, ah * 4 + w);

    // fragment offsets
    const int lane = t & 63, wid = t >> 6;
    const int wm = wid & 1, wn = wid >> 1;
    const int m16 = lane & 15, g = lane >> 4;
    int offA[2][4], offB[2][4];
#pragma unroll
    for (int ks = 0; ks < 2; ++ks)
#pragma unroll
        for (int i = 0; i < 4; ++i) {
            offA[ks][i] = IDX64(wm * 64 + i * 16 + m16, ks * 4 + g);
            offB[ks][i] = IDX64(wn * 64 + i * 16 + m16, ks * 4 + g);
        }

    const f32x4 zf = {0.f, 0.f, 0.f, 0.f};
    f32x4 acc1[4][4], acc3[4][4];
#pragma unroll
    for (int i = 0; i < 4; ++i)
#pragma unroll
        for (int j = 0; j < 4; ++j) { acc1[i][j] = zf; acc3[i][j] = zf; }

    for (int kt = 0; kt < 16; ++kt) {
        float4 av[8];
#pragma unroll
        for (int w = 0; w < 8; ++w) av[w] = *(const float4*)(Ap + kt * 64 + w * 4);
        __syncthreads();
#pragma unroll
        for (int c = 0; c < 4; ++c) {
            gll16(g1 + kt * 8192 + c * 2048, &B1s[c * 2048 + t * 8]);
            gll16(g3 + kt * 8192 + c * 2048, &B3s[c * 2048 + t * 8]);
        }
#pragma unroll
        for (int w = 0; w < 4; ++w) {
            uint4 aw = { pk2(av[2*w].x, av[2*w].y),     pk2(av[2*w].z, av[2*w].w),
                         pk2(av[2*w+1].x, av[2*w+1].y), pk2(av[2*w+1].z, av[2*w+1].w) };
            *(uint4*)&As[aoff[w]] = aw;
        }
        __syncthreads();   // drains vmcnt (gll) + lgkm
#pragma unroll
        for (int ks = 0; ks < 2; ++ks) {
            short8 af[4], b1f[4], b3f[4];
#pragma unroll
            for (int i = 0; i < 4; ++i) {
                af[i]  = *(const short8*)&As [offA[ks][i]];
                b1f[i] = *(const short8*)&B1s[offB[ks][i]];
                b3f[i] = *(const short8*)&B3s[offB[ks][i]];
            }
#pragma unroll
            for (int i = 0; i < 4; ++i)
#pragma unroll
                for (int j = 0; j < 4; ++j) {
                    acc1[i][j] = __builtin_amdgcn_mfma_f32_16x16x32_bf16(af[i], b1f[j], acc1[i][j], 0, 0, 0);
                    acc3[i][j] = __builtin_amdgcn_mfma_f32_16x16x32_bf16(af[i], b3f[j], acc3[i][j], 0, 0, 0);
                }
        }
    }

#pragma unroll
    for (int j = 0; j < 4; ++j) {
        const int gcol = nb + wn * 64 + j * 16 + m16;
        const float bb1 = B1[gcol];
        const float bb3 = B3[gcol];
#pragma unroll
        for (int i = 0; i < 4; ++i) {
            const int growb = row0 + wm * 64 + i * 16 + g * 4;
#pragma unroll
            for (int r = 0; r < 4; ++r) {
                float x1 = acc1[i][j][r] + bb1;
                float x3 = acc3[i][j][r] + bb3;
                float h = x1 / (1.f + __expf(-x1)) * x3;
                Hb[(size_t)(growb + r) * INTER + gcol] = f2bf(h);
            }
        }
    }
}

// ---------------- out (+)= w * (H@W2 + b2), BK=64, gll B-staging -----------
template <bool ROUTED>
__global__ __launch_bounds__(256, 2)
void k_out(const ushort* __restrict__ Hin,
           const ushort* __restrict__ W2t, const float* __restrict__ B2,
           float* __restrict__ out,
           const int* __restrict__ rowid, const int* __restrict__ offs,
           const int* __restrict__ cnt, const float* __restrict__ rowwt)
{
    __shared__ __align__(16) ushort As[128 * 64];
    __shared__ __align__(16) ushort Bs[128 * 64];

    const int nbx  = blockIdx.x;
    const int nb   = nbx * 128;
    const int row0 = blockIdx.y * 128;

    int rstart = 0, rcount = T_TOK;
    const ushort* w2 = W2t;
    if constexpr (ROUTED) {
        const int total = offs[NEXP];
        if (row0 >= total) return;
        int e = 0;
        while (offs[e + 1] <= row0) ++e;
        rstart = offs[e]; rcount = cnt[e];
        w2 += (size_t)e << 20; B2 += e * D_MODEL;
    }
    const int t = threadIdx.x;
    const ushort* g2 = w2 + (size_t)(nbx * 16) * 8192 + t * 8;

    const int arow = t >> 1, ah = t & 1;
    const ushort* Ap = Hin + (size_t)(row0 + arow) * INTER + ah * 32;
    int aoff[4];
#pragma unroll
    for (int w = 0; w < 4; ++w) aoff[w] = IDX64(arow, ah * 4 + w);

    const int lane = t & 63, wid = t >> 6;
    const int wm = wid & 1, wn = wid >> 1;
    const int m16 = lane & 15, g = lane >> 4;
    int offA[2][4], offB[2][4];
#pragma unroll
    for (int ks = 0; ks < 2; ++ks)
#pragma unroll
        for (int i = 0; i < 4; ++i) {
            offA[ks][i] = IDX64(wm * 64 + i * 16 + m16, ks * 4 + g);
            offB[ks][i] = IDX64(wn * 64 + i * 16 + m16, ks * 4 + g);
        }

    const f32x4 zf = {0.f, 0.f, 0.f, 0.f};
    f32x4 acc[4][4];
#pragma unroll
    for (int i = 0; i < 4; ++i)
#pragma unroll
        for (int j = 0; j < 4; ++j) acc[i][j] = zf;

    for (int kt = 0; kt < 16; ++kt) {
        uint4 av[4];
#pragma unroll
        for (int w = 0; w < 4; ++w) av[w] = *(const uint4*)(Ap + kt * 64 + w * 8);
        __syncthreads();
#pragma unroll
        for (int c = 0; c < 4; ++c)
            gll16(g2 + kt * 8192 + c * 2048, &Bs[c * 2048 + t * 8]);
#pragma unroll
        for (int w = 0; w < 4; ++w)
            *(uint4*)&As[aoff[w]] = av[w];
        __syncthreads();
#pragma unroll
        for (int ks = 0; ks < 2; ++ks) {
            short8 af[4], bf[4];
#pragma unroll
            for (int i = 0; i < 4; ++i) {
                af[i] = *(const short8*)&As[offA[ks][i]];
                bf[i] = *(const short8*)&Bs[offB[ks][i]];
            }
#pragma unroll
            for (int i = 0; i < 4; ++i)
#pragma unroll
                for (int j = 0; j < 4; ++j)
                    acc[i][j] = __builtin_amdgcn_mfma_f32_16x16x32_bf16(af[i], bf[j], acc[i][j], 0, 0, 0);
        }
    }

#pragma unroll
    for (int i = 0; i < 4; ++i) {
#pragma unroll
        for (int r = 0; r < 4; ++r) {
            const int grow = row0 + wm * 64 + i * 16 + g * 4 + r;
            int tok = grow; float wt = 1.f; bool valid = true;
            if constexpr (ROUTED) {
                valid = (grow - rstart) < rcount;
                if (valid) { tok = rowid[grow]; wt = rowwt[grow]; }
            }
            if (!valid) continue;
#pragma unroll
            for (int j = 0; j < 4; ++j) {
                const int gcol = nb + wn * 64 + j * 16 + m16;
                float v = acc[i][j][r] + B2[gcol];
                if constexpr (ROUTED) {
                    atomicAdd(out + (size_t)tok * D_MODEL + gcol, wt * v);
                } else {
                    out[(size_t)grow * D_MODEL + gcol] = v;
                }
            }
        }
    }
}

// ---------------- launcher ----------------
// ws map (bytes):
//   [0,32)        cnt        [64,96)   cnt2      [128,164) offs
//   [256,65792)   topk_idx   [65792,131328) topk_w
//   [131328,200960) rowid    [200960,270592) rowwt
//   [524288, 36175872)  Hb  (ROWCAP*2048 = 35.65 MB)   -- MUST stay above rowwt end!
//   [36175872, 52953088) WA (16 MB)   [52953088, 69730304) WB (16 MB)
extern "C" void kernel_launch(void* const* d_in, const int* in_sizes, int n_in,
                              void* d_out, int out_size, void* d_ws, size_t ws_size,
                              hipStream_t stream)
{
    const float* x   = (const float*)d_in[0];
    const float* gw  = (const float*)d_in[1];
    const float* w1  = (const float*)d_in[2];
    const float* b1  = (const float*)d_in[3];
    const float* w2  = (const float*)d_in[4];
    const float* b2  = (const float*)d_in[5];
    const float* w3  = (const float*)d_in[6];
    const float* b3  = (const float*)d_in[7];
    const float* sw1 = (const float*)d_in[8];
    const float* sb1 = (const float*)d_in[9];
    const float* sw2 = (const float*)d_in[10];
    const float* sb2 = (const float*)d_in[11];
    const float* sw3 = (const float*)d_in[12];
    const float* sb3 = (const float*)d_in[13];
    float* out = (float*)d_out;

    char* ws = (char*)d_ws;
    int*   cnt      = (int*)(ws);
    int*   cnt2     = (int*)(ws + 64);
    int*   offs     = (int*)(ws + 128);
    int*   topk_idx = (int*)(ws + 256);
    float* topk_w   = (float*)(ws + 256 + 65536);
    int*   rowid    = (int*)(ws + 256 + 131072);
    float* rowwt    = (float*)(ws + 256 + 131072 + ROWCAP * 4);
    ushort* Hb = (ushort*)(ws + 524288);                         // clear of rowwt end (270,592)
    ushort* WA = (ushort*)(ws + 524288 + (size_t)ROWCAP * 2048); // 36,175,872
    ushort* WB = WA + (8u << 20);                                // +16 MB
    ushort* sw1t = WB;
    ushort* sw3t = WB + (1 << 20);
    ushort* sw2t = WA;
    ushort* w1t  = WA;
    ushort* w3t  = WB;
    ushort* w2t  = WA;

    hipMemsetAsync(ws, 0, 256, stream);

    k_gate<<<256, 256, 0, stream>>>(x, gw, topk_idx, topk_w, cnt);
    k_prefix<<<1, 64, 0, stream>>>(cnt, offs);
    k_scatter<<<32, 256, 0, stream>>>(topk_idx, topk_w, offs, cnt2, rowid, rowwt);

    // shared expert
    k_tw<<<dim3(128, 2), 256, 0, stream>>>(sw1, sw1t, sw3, sw3t, 1);
    k_h<false><<<dim3(8, 64), 256, 0, stream>>>(x, sw1t, sb1, sw3t, sb3, Hb,
                                                nullptr, nullptr, nullptr);
    k_tw<<<dim3(128, 1), 256, 0, stream>>>(sw2, sw2t, sw2, sw2t, 1);
    k_out<false><<<dim3(8, 64), 256, 0, stream>>>(Hb, sw2t, sb2, out,
                                                  nullptr, nullptr, nullptr, nullptr);

    // routed experts
    k_tw<<<dim3(128, 16), 256, 0, stream>>>(w1, w1t, w3, w3t, 8);
    k_h<true><<<dim3(8, ROWCAP / 128), 256, 0, stream>>>(x, w1t, b1, w3t, b3, Hb,
                                                         rowid, offs, cnt);
    k_tw<<<dim3(128, 8), 256, 0, stream>>>(w2, w2t, w2, w2t, 8);
    k_out<true><<<dim3(8, ROWCAP / 128), 256, 0, stream>>>(Hb, w2t, b2, out,
                                                           rowid, offs, cnt, rowwt);
}